// Round 18
// baseline (125.034 us; speedup 1.0000x reference)
//
#include <hip/hip_runtime.h>
#include <hip/hip_bf16.h>

#define B_ 2
#define T_ 2048
#define C_ 1024
#define H_ 16
#define D_ 64
#define M_ (B_*T_)          // 4096 rows
#define SCALE_ 0.125f       // 1/sqrt(64)
#define LOG2E_ 1.44269504f
#define NEG_ (-1e30f)
#define THR_ 8.0f           // defer-max threshold (log2 units)

typedef __bf16 bf16;
typedef __bf16 bf16x4 __attribute__((ext_vector_type(4)));
typedef __bf16 bf16x8 __attribute__((ext_vector_type(8)));
typedef float  f32x4  __attribute__((ext_vector_type(4)));

#define XB_ELEMS  ((size_t)M_*C_)        // 4,194,304
#define W_ELEMS   ((size_t)C_*C_)        // 1,048,576
#define NSLOT     2048                   // 32 qt x 32 bh x 2 halves
#define ML_FLOATS ((size_t)NSLOT*64*2)   // 262,144 floats = 1 MB

__device__ __forceinline__ void glds16(const void* g, void* l) {
  __builtin_amdgcn_global_load_lds((const __attribute__((address_space(1))) void*)g,
                                   (__attribute__((address_space(3))) void*)l,
                                   16, 0, 0);
}

// ---------------------------------------------------------------------------
// f32 -> bf16 conversion pass (r16 version).
// ---------------------------------------------------------------------------
__global__ __launch_bounds__(256)
void cvt5(const float* __restrict__ x,  const float* __restrict__ wq,
          const float* __restrict__ wk, const float* __restrict__ wv,
          const float* __restrict__ wo, bf16* __restrict__ out,
          bf16* __restrict__ wodst) {
  int bid = blockIdx.x;
  const float* src; bf16* dst; size_t off;
  if (bid < 2048)      { src = x;  dst = out;                         off = (size_t)bid*2048; }
  else if (bid < 2560) { src = wq; dst = out + XB_ELEMS;              off = (size_t)(bid-2048)*2048; }
  else if (bid < 3072) { src = wk; dst = out + XB_ELEMS +   W_ELEMS;  off = (size_t)(bid-2560)*2048; }
  else if (bid < 3584) { src = wv; dst = out + XB_ELEMS + 2*W_ELEMS;  off = (size_t)(bid-3072)*2048; }
  else                 { src = wo; dst = wodst;                       off = (size_t)(bid-3584)*2048; }
  size_t i = off + (size_t)threadIdx.x * 8;
  f32x4 lo = *(const f32x4*)(src + i);
  f32x4 hi = *(const f32x4*)(src + i + 4);
  bf16x8 r;
  #pragma unroll
  for (int t = 0; t < 4; ++t) { r[t] = (bf16)lo[t]; r[t+4] = (bf16)hi[t]; }
  *(bf16x8*)(dst + i) = r;
}

// ---------------------------------------------------------------------------
// NT GEMM (r17 version): 128x128 tile, BK=64, 4 waves, glds16 pre-swizzled
// source + XOR-swizzled reads. 16 K-iterations.
// ---------------------------------------------------------------------------
template<int OUTMODE>
__global__ __launch_bounds__(256)
void gemm_nt(const bf16* __restrict__ Ab,
             const bf16* __restrict__ W0, const bf16* __restrict__ W1,
             const bf16* __restrict__ W2,
             void* __restrict__ O0v, void* __restrict__ O1v, void* __restrict__ O2v,
             int K) {
  __shared__ __align__(16) bf16 As[128*64];
  __shared__ __align__(16) bf16 Bs[128*64];

  const bf16* W = W0;
  void* Ov = O0v;
  bool vtrans = false;
  float oscale = 1.0f;
  if constexpr (OUTMODE == 0) {
    if (blockIdx.z == 0)      { oscale = SCALE_ * LOG2E_; }
    else if (blockIdx.z == 1) { W = W1; Ov = O1v; }
    else                      { W = W2; Ov = O2v; vtrans = true; }
  }

  const int m0 = blockIdx.y * 128, n0 = blockIdx.x * 128;
  const int tid = threadIdx.x, wid = tid >> 6, lane = tid & 63;
  const int wm = wid >> 1, wn = wid & 1;
  const int l15 = lane & 15, grp = lane >> 4;

  f32x4 acc[4][4] = {};

  const int lr8 = lane >> 3;
  const int lkswz = ((lane & 7) ^ lr8) * 8;
  const bf16* Ag = Ab + (size_t)(m0 + wid*8 + lr8) * K + lkswz;
  const bf16* Bg = W  + (size_t)(n0 + wid*8 + lr8) * K + lkswz;

  const int amRow = wm*64 + l15;
  const int bnRow = wn*64 + l15;
  const int swz = l15 & 7;

  for (int k0 = 0; k0 < K; k0 += 64) {
    __syncthreads();
    #pragma unroll
    for (int c = 0; c < 4; ++c) {
      glds16(Ag + (size_t)(c*32)*K + k0, As + (wid + c*4)*512);
      glds16(Bg + (size_t)(c*32)*K + k0, Bs + (wid + c*4)*512);
    }
    __syncthreads();

    #pragma unroll
    for (int ks = 0; ks < 2; ++ks) {
      const int aslot = ((ks*4 + grp) ^ swz) * 8;
      bf16x8 af[4], bfr[4];
      #pragma unroll
      for (int i = 0; i < 4; ++i) {
        af[i]  = *(const bf16x8*)(As + (amRow + i*16)*64 + aslot);
        bfr[i] = *(const bf16x8*)(Bs + (bnRow + i*16)*64 + aslot);
      }
      __builtin_amdgcn_s_setprio(1);
      #pragma unroll
      for (int i = 0; i < 4; ++i)
        #pragma unroll
        for (int j = 0; j < 4; ++j)
          acc[i][j] = __builtin_amdgcn_mfma_f32_16x16x32_bf16(af[i], bfr[j], acc[i][j], 0, 0, 0);
      __builtin_amdgcn_s_setprio(0);
    }
  }

  const int rBase = m0 + wm*64 + grp * 4;
  const int cBase = n0 + wn*64 + l15;
  #pragma unroll
  for (int fm = 0; fm < 4; ++fm) {
    #pragma unroll
    for (int fn = 0; fn < 4; ++fn) {
      #pragma unroll
      for (int j = 0; j < 4; ++j) {
        int m = rBase + fm*16 + j;
        int n = cBase + fn*16;
        if constexpr (OUTMODE == 0) {
          int b = m >> 11, t = m & 2047, h = n >> 6, d = n & 63;
          size_t idx = vtrans ? (((size_t)(b*H_ + h) * D_ + d) * T_ + t)
                              : (((size_t)(b*H_ + h) * T_ + t) * D_ + d);
          ((bf16*)Ov)[idx] = (bf16)(acc[fm][fn][j] * oscale);
        } else {
          ((float*)Ov)[(size_t)m * C_ + n] = acc[fm][fn][j];
        }
      }
    }
  }
}

// ---------------------------------------------------------------------------
// SPLIT-K flash attention. Grid 2048: qt = 31-(id>>6), half = (id>>5)&1,
// bh = id&31. Lower half covers kt [0, qt/2+1), upper [qt/2+1, qt+1).
// Writes UNNORMALIZED partial O (bf16) to pO[slot] and (m,l) to ml[slot].
// slot = (qt*32+bh)*2 + half.
// ---------------------------------------------------------------------------
#define LKV 72

__global__ __launch_bounds__(256)
void attn_split(const bf16* __restrict__ Q, const bf16* __restrict__ Km,
                const bf16* __restrict__ Vt, bf16* __restrict__ pO,
                float* __restrict__ ml) {
  __shared__ __align__(16) bf16 Ks [64*LKV];
  __shared__ __align__(16) bf16 Vts[64*LKV];
  __shared__ __align__(16) bf16 Ps [64*LKV];

  const int id = blockIdx.x;
  const int qt = 31 - (id >> 6);
  const int half = (id >> 5) & 1;
  const int bh = id & 31;
  const int q0 = qt * 64;
  const int nl = (qt >> 1) + 1;
  const int k0t = half ? nl : 0;
  const int k1t = half ? (qt + 1) : nl;
  const int slot = (qt*32 + bh)*2 + half;

  const int tid = threadIdx.x, wid = tid >> 6, lane = tid & 63;
  const int l15 = lane & 15;
  const int grp = lane >> 4;
  const int myrow4 = grp * 4;

  if (k0t >= k1t) {                       // empty range (qt=0 upper)
    if (grp == 0 && wid < 4) {
      int row = wid*16 + l15;
      ml[(size_t)slot*128 + row*2    ] = NEG_;
      ml[(size_t)slot*128 + row*2 + 1] = 0.f;
    }
    return;
  }

  const bf16* Qb = Q  + (size_t)bh * T_ * D_;
  const bf16* Kb = Km + (size_t)bh * T_ * D_;
  const bf16* Vb = Vt + (size_t)bh * D_ * T_;

  const int ksr = tid >> 3, kskc = tid & 7;
  const int kSlot = grp * 8;

  const int qrow = q0 + wid*16 + l15;
  bf16x8 aq0 = *(const bf16x8*)(Qb + (size_t)qrow*64 +      grp*8);
  bf16x8 aq1 = *(const bf16x8*)(Qb + (size_t)qrow*64 + 32 + grp*8);

  f32x4 oacc[4] = {};
  float m_s = NEG_, l_s = 0.f;

  const int kvS = k0t * 64;
  bf16x8 kv_a = *(const bf16x8*)(Kb + (size_t)(kvS + ksr)*64      + kskc*8);
  bf16x8 kv_b = *(const bf16x8*)(Kb + (size_t)(kvS + ksr + 32)*64 + kskc*8);
  bf16x8 vt_a = *(const bf16x8*)(Vb + (size_t)(ksr     )*T_ + kvS + kskc*8);
  bf16x8 vt_b = *(const bf16x8*)(Vb + (size_t)(ksr + 32)*T_ + kvS + kskc*8);

  for (int kt = k0t; kt < k1t; ++kt) {
    const int kv0 = kt * 64;

    __syncthreads();
    *(bf16x8*)(Ks  + ksr*LKV      + kskc*8) = kv_a;
    *(bf16x8*)(Ks  + (ksr+32)*LKV + kskc*8) = kv_b;
    *(bf16x8*)(Vts + ksr*LKV      + kskc*8) = vt_a;
    *(bf16x8*)(Vts + (ksr+32)*LKV + kskc*8) = vt_b;
    __syncthreads();

    {
      const int kn = (kt + 1 < k1t) ? kv0 + 64 : kv0;
      kv_a = *(const bf16x8*)(Kb + (size_t)(kn + ksr)*64      + kskc*8);
      kv_b = *(const bf16x8*)(Kb + (size_t)(kn + ksr + 32)*64 + kskc*8);
      vt_a = *(const bf16x8*)(Vb + (size_t)(ksr     )*T_ + kn + kskc*8);
      vt_b = *(const bf16x8*)(Vb + (size_t)(ksr + 32)*T_ + kn + kskc*8);
    }

    f32x4 s[4];
    __builtin_amdgcn_s_setprio(1);
    #pragma unroll
    for (int n = 0; n < 4; ++n) {
      int row = n*16 + l15;
      bf16x8 bk0 = *(const bf16x8*)(Ks + row*LKV      + kSlot);
      bf16x8 bk1 = *(const bf16x8*)(Ks + row*LKV + 32 + kSlot);
      f32x4 a = {};
      a = __builtin_amdgcn_mfma_f32_16x16x32_bf16(bk0, aq0, a, 0, 0, 0);
      a = __builtin_amdgcn_mfma_f32_16x16x32_bf16(bk1, aq1, a, 0, 0, 0);
      s[n] = a;
    }
    __builtin_amdgcn_s_setprio(0);

    float pmax = NEG_;
    if (kt == qt) {
      #pragma unroll
      for (int n = 0; n < 4; ++n)
        #pragma unroll
        for (int j = 0; j < 4; ++j) {
          int kvg = kv0 + n*16 + myrow4 + j;
          float sv = (kvg <= qrow) ? s[n][j] : NEG_;
          s[n][j] = sv;
          pmax = fmaxf(pmax, sv);
        }
    } else {
      #pragma unroll
      for (int n = 0; n < 4; ++n)
        #pragma unroll
        for (int j = 0; j < 4; ++j) pmax = fmaxf(pmax, s[n][j]);
    }
    pmax = fmaxf(pmax, __shfl_xor(pmax, 16));
    pmax = fmaxf(pmax, __shfl_xor(pmax, 32));

    if (__any(pmax > m_s + THR_)) {
      float mnew = fmaxf(m_s, pmax);
      float scold = __builtin_amdgcn_exp2f(m_s - mnew);
      m_s = mnew;
      l_s *= scold;
      #pragma unroll
      for (int j = 0; j < 4; ++j) {
        float scj = __shfl(scold, myrow4 + j);
        #pragma unroll
        for (int n = 0; n < 4; ++n) oacc[n][j] *= scj;
      }
    }

    float ps = 0.f;
    #pragma unroll
    for (int n = 0; n < 4; ++n) {
      bf16x4 pw;
      #pragma unroll
      for (int j = 0; j < 4; ++j) {
        float p = __builtin_amdgcn_exp2f(s[n][j] - m_s);
        ps += p;
        pw[j] = (bf16)p;
      }
      *(bf16x4*)(Ps + (size_t)(wid*16 + l15)*LKV + n*16 + myrow4) = pw;
    }
    ps += __shfl_xor(ps, 16);
    ps += __shfl_xor(ps, 32);
    l_s += ps;

    asm volatile("s_waitcnt lgkmcnt(0)" ::: "memory");
    __builtin_amdgcn_sched_barrier(0);

    int parow = wid*16 + l15;
    bf16x8 pa0 = *(const bf16x8*)(Ps + parow*LKV      + kSlot);
    bf16x8 pa1 = *(const bf16x8*)(Ps + parow*LKV + 32 + kSlot);
    __builtin_amdgcn_s_setprio(1);
    #pragma unroll
    for (int n = 0; n < 4; ++n) {
      int vrow = n*16 + l15;
      bf16x8 bv0 = *(const bf16x8*)(Vts + vrow*LKV      + kSlot);
      bf16x8 bv1 = *(const bf16x8*)(Vts + vrow*LKV + 32 + kSlot);
      oacc[n] = __builtin_amdgcn_mfma_f32_16x16x32_bf16(pa0, bv0, oacc[n], 0, 0, 0);
      oacc[n] = __builtin_amdgcn_mfma_f32_16x16x32_bf16(pa1, bv1, oacc[n], 0, 0, 0);
    }
    __builtin_amdgcn_s_setprio(0);
  }

  // epilogue: write unnormalized partial O (bf16) + per-row (m,l)
  bf16* po = pO + (size_t)slot * 4096;
  #pragma unroll
  for (int j = 0; j < 4; ++j) {
    int row = wid*16 + myrow4 + j;
    #pragma unroll
    for (int n = 0; n < 4; ++n)
      po[row*64 + n*16 + l15] = (bf16)oacc[n][j];
  }
  if (grp == 0) {
    int row = wid*16 + l15;
    ml[(size_t)slot*128 + row*2    ] = m_s;
    ml[(size_t)slot*128 + row*2 + 1] = l_s;
  }
}

// ---------------------------------------------------------------------------
// Combine: merge the two partial halves per (qt,bh,row) -> ao [B,T,C] bf16.
// Grid 256 x 256 threads; thread = one 64-wide row.
// ---------------------------------------------------------------------------
__global__ __launch_bounds__(256)
void combine(const bf16* __restrict__ pO, const float* __restrict__ ml,
             bf16* __restrict__ ao) {
  int g = blockIdx.x * 256 + threadIdx.x;  // 0..65535
  int pair = g >> 6, r = g & 63;
  int qt = pair >> 5, bh = pair & 31;
  int s1 = pair*2, s2 = pair*2 + 1;
  float m1 = ml[(size_t)s1*128 + r*2], l1 = ml[(size_t)s1*128 + r*2 + 1];
  float m2 = ml[(size_t)s2*128 + r*2], l2 = ml[(size_t)s2*128 + r*2 + 1];
  float M  = fmaxf(m1, m2);
  float w1 = __builtin_amdgcn_exp2f(m1 - M);
  float w2 = __builtin_amdgcn_exp2f(m2 - M);
  float inv = 1.f / (w1*l1 + w2*l2);
  w1 *= inv; w2 *= inv;
  const bf16* p1 = pO + (size_t)s1*4096 + r*64;
  const bf16* p2 = pO + (size_t)s2*4096 + r*64;
  int b = bh >> 4, h = bh & 15, t = qt*64 + r;
  bf16* dst = ao + ((size_t)(b*T_ + t))*C_ + h*64;
  #pragma unroll
  for (int c = 0; c < 8; ++c) {
    bf16x8 a = *(const bf16x8*)(p1 + c*8);
    bf16x8 bq = *(const bf16x8*)(p2 + c*8);
    bf16x8 o;
    #pragma unroll
    for (int j = 0; j < 8; ++j)
      o[j] = (bf16)(w1*(float)a[j] + w2*(float)bq[j]);
    *(bf16x8*)(dst + c*8) = o;
  }
}

// ---------------------------------------------------------------------------
// Fallback mono attention (r17 version, used when ws is too small).
// ---------------------------------------------------------------------------
__global__ __launch_bounds__(256)
void attn_fwd(const bf16* __restrict__ Q, const bf16* __restrict__ Km,
              const bf16* __restrict__ Vt, bf16* __restrict__ Oa) {
  __shared__ __align__(16) bf16 Ks [64*LKV];
  __shared__ __align__(16) bf16 Vts[64*LKV];
  __shared__ __align__(16) bf16 Ps [64*LKV];

  const int id = blockIdx.x;
  const int qt = 31 - (id >> 5);
  const int bh = id & 31;
  const int q0 = qt * 64;
  const int tid = threadIdx.x, wid = tid >> 6, lane = tid & 63;
  const int l15 = lane & 15;
  const int grp = lane >> 4;
  const int myrow4 = grp * 4;

  const bf16* Qb = Q  + (size_t)bh * T_ * D_;
  const bf16* Kb = Km + (size_t)bh * T_ * D_;
  const bf16* Vb = Vt + (size_t)bh * D_ * T_;

  const int ksr = tid >> 3, kskc = tid & 7;
  const int kSlot = grp * 8;
  const int b = bh >> 4, h = bh & 15;

  const int qrow = q0 + wid*16 + l15;
  bf16x8 aq0 = *(const bf16x8*)(Qb + (size_t)qrow*64 +      grp*8);
  bf16x8 aq1 = *(const bf16x8*)(Qb + (size_t)qrow*64 + 32 + grp*8);

  f32x4 oacc[4] = {};
  float m_s = NEG_, l_s = 0.f;

  bf16x8 kv_a = *(const bf16x8*)(Kb + (size_t)(ksr)*64      + kskc*8);
  bf16x8 kv_b = *(const bf16x8*)(Kb + (size_t)(ksr + 32)*64 + kskc*8);
  bf16x8 vt_a = *(const bf16x8*)(Vb + (size_t)(ksr     )*T_ + kskc*8);
  bf16x8 vt_b = *(const bf16x8*)(Vb + (size_t)(ksr + 32)*T_ + kskc*8);

  for (int kt = 0; kt <= qt; ++kt) {
    const int kv0 = kt * 64;
    __syncthreads();
    *(bf16x8*)(Ks  + ksr*LKV      + kskc*8) = kv_a;
    *(bf16x8*)(Ks  + (ksr+32)*LKV + kskc*8) = kv_b;
    *(bf16x8*)(Vts + ksr*LKV      + kskc*8) = vt_a;
    *(bf16x8*)(Vts + (ksr+32)*LKV + kskc*8) = vt_b;
    __syncthreads();

    {
      const int kn = (kt < qt) ? kv0 + 64 : kv0;
      kv_a = *(const bf16x8*)(Kb + (size_t)(kn + ksr)*64      + kskc*8);
      kv_b = *(const bf16x8*)(Kb + (size_t)(kn + ksr + 32)*64 + kskc*8);
      vt_a = *(const bf16x8*)(Vb + (size_t)(ksr     )*T_ + kn + kskc*8);
      vt_b = *(const bf16x8*)(Vb + (size_t)(ksr + 32)*T_ + kn + kskc*8);
    }

    f32x4 s[4];
    __builtin_amdgcn_s_setprio(1);
    #pragma unroll
    for (int n = 0; n < 4; ++n) {
      int row = n*16 + l15;
      bf16x8 bk0 = *(const bf16x8*)(Ks + row*LKV      + kSlot);
      bf16x8 bk1 = *(const bf16x8*)(Ks + row*LKV + 32 + kSlot);
      f32x4 a = {};
      a = __builtin_amdgcn_mfma_f32_16x16x32_bf16(bk0, aq0, a, 0, 0, 0);
      a = __builtin_amdgcn_mfma_f32_16x16x32_bf16(bk1, aq1, a, 0, 0, 0);
      s[n] = a;
    }
    __builtin_amdgcn_s_setprio(0);

    float pmax = NEG_;
    if (kt == qt) {
      #pragma unroll
      for (int n = 0; n < 4; ++n)
        #pragma unroll
        for (int j = 0; j < 4; ++j) {
          int kvg = kv0 + n*16 + myrow4 + j;
          float sv = (kvg <= qrow) ? s[n][j] : NEG_;
          s[n][j] = sv;
          pmax = fmaxf(pmax, sv);
        }
    } else {
      #pragma unroll
      for (int n = 0; n < 4; ++n)
        #pragma unroll
        for (int j = 0; j < 4; ++j) pmax = fmaxf(pmax, s[n][j]);
    }
    pmax = fmaxf(pmax, __shfl_xor(pmax, 16));
    pmax = fmaxf(pmax, __shfl_xor(pmax, 32));

    if (__any(pmax > m_s + THR_)) {
      float mnew = fmaxf(m_s, pmax);
      float scold = __builtin_amdgcn_exp2f(m_s - mnew);
      m_s = mnew;
      l_s *= scold;
      #pragma unroll
      for (int j = 0; j < 4; ++j) {
        float scj = __shfl(scold, myrow4 + j);
        #pragma unroll
        for (int n = 0; n < 4; ++n) oacc[n][j] *= scj;
      }
    }

    float ps = 0.f;
    #pragma unroll
    for (int n = 0; n < 4; ++n) {
      bf16x4 pw;
      #pragma unroll
      for (int j = 0; j < 4; ++j) {
        float p = __builtin_amdgcn_exp2f(s[n][j] - m_s);
        ps += p;
        pw[j] = (bf16)p;
      }
      *(bf16x4*)(Ps + (size_t)(wid*16 + l15)*LKV + n*16 + myrow4) = pw;
    }
    ps += __shfl_xor(ps, 16);
    ps += __shfl_xor(ps, 32);
    l_s += ps;

    asm volatile("s_waitcnt lgkmcnt(0)" ::: "memory");
    __builtin_amdgcn_sched_barrier(0);

    int parow = wid*16 + l15;
    bf16x8 pa0 = *(const bf16x8*)(Ps + parow*LKV      + kSlot);
    bf16x8 pa1 = *(const bf16x8*)(Ps + parow*LKV + 32 + kSlot);
    __builtin_amdgcn_s_setprio(1);
    #pragma unroll
    for (int n = 0; n < 4; ++n) {
      int vrow = n*16 + l15;
      bf16x8 bv0 = *(const bf16x8*)(Vts + vrow*LKV      + kSlot);
      bf16x8 bv1 = *(const bf16x8*)(Vts + vrow*LKV + 32 + kSlot);
      oacc[n] = __builtin_amdgcn_mfma_f32_16x16x32_bf16(pa0, bv0, oacc[n], 0, 0, 0);
      oacc[n] = __builtin_amdgcn_mfma_f32_16x16x32_bf16(pa1, bv1, oacc[n], 0, 0, 0);
    }
    __builtin_amdgcn_s_setprio(0);
  }

  const int tg = q0 + wid*16 + myrow4;
  #pragma unroll
  for (int j = 0; j < 4; ++j) {
    float lj = __shfl(l_s, myrow4 + j);
    float inv = 1.f / lj;
    int trow = tg + j;
    #pragma unroll
    for (int n = 0; n < 4; ++n) {
      int ch = h*64 + n*16 + l15;
      Oa[((size_t)(b*T_ + trow)) * C_ + ch] = (bf16)(oacc[n][j] * inv);
    }
  }
}

// ---------------------------------------------------------------------------
extern "C" void kernel_launch(void* const* d_in, const int* in_sizes, int n_in,
                              void* d_out, int out_size, void* d_ws, size_t ws_size,
                              hipStream_t stream) {
  const float* x  = (const float*)d_in[0];
  const float* wq = (const float*)d_in[1];
  const float* wk = (const float*)d_in[2];
  const float* wv = (const float*)d_in[3];
  const float* wo = (const float*)d_in[4];

  bf16* q  = (bf16*)d_ws;                    // [B,H,T,D] bf16 (Q pre-scaled)
  bf16* k  = q  + XB_ELEMS;
  bf16* v  = k  + XB_ELEMS;                  // [B,H,D,T] bf16 (transposed)

  bf16* cvtbuf = (bf16*)d_out;               // bf16 staging inside d_out
  bf16* xb  = cvtbuf;
  bf16* wqb = cvtbuf + XB_ELEMS;
  bf16* wkb = wqb + W_ELEMS;
  bf16* wvb = wkb + W_ELEMS;
  bf16* wob_stage = wvb + W_ELEMS;           // fallback wo staging (in d_out)

  const size_t need_split = (4*XB_ELEMS + W_ELEMS)*sizeof(bf16) + ML_FLOATS*sizeof(float);
  const size_t need_big   = (4*XB_ELEMS + W_ELEMS)*sizeof(bf16);
  const bool splitws = ws_size >= need_split;
  const bool bigws   = ws_size >= need_big;

  bf16* ao  = bigws ? (v + XB_ELEMS) : xb;
  bf16* wob = bigws ? (v + 2*XB_ELEMS) : wob_stage;
  float* ml = (float*)(v + 2*XB_ELEMS + W_ELEMS);   // valid only if splitws

  dim3 blk(256);
  // 0) convert all f32 inputs to bf16
  cvt5<<<dim3(4096), blk, 0, stream>>>(x, wq, wk, wv, wo, cvtbuf, wob);
  // 1) QKV projections: xb @ W^T -> q,k,v
  gemm_nt<0><<<dim3(C_/128, M_/128, 3), blk, 0, stream>>>(xb, wqb, wkb, wvb,
                                                          q, k, v, C_);
  bf16* aoSrc = ao;
  if (splitws) {
    // 2a) split-K attention: partials into d_out (staging dead), ml into ws
    bf16* pO = (bf16*)d_out;
    attn_split<<<dim3(2048), blk, 0, stream>>>(q, k, v, pO, ml);
    // 2b) combine halves -> ao (ws)
    combine<<<dim3(256), blk, 0, stream>>>(pO, ml, ao);
  } else {
    // fallback: mono attention
    attn_fwd<<<dim3(1024), blk, 0, stream>>>(q, k, v, ao);
    if (!bigws) {
      hipMemcpyAsync(q, xb,        XB_ELEMS * sizeof(bf16), hipMemcpyDeviceToDevice, stream);
      hipMemcpyAsync(k, wob_stage, W_ELEMS  * sizeof(bf16), hipMemcpyDeviceToDevice, stream);
      aoSrc = q; wob = k;
    }
  }
  // 3) output projection: ao @ wo^T -> f32 d_out
  gemm_nt<1><<<dim3(C_/128, M_/128, 1), blk, 0, stream>>>(aoSrc, wob, nullptr, nullptr,
                                                          d_out, nullptr, nullptr, C_);
}

// Round 19
// 114.502 us; speedup vs baseline: 1.0920x; 1.0920x over previous
//
#include <hip/hip_runtime.h>
#include <hip/hip_bf16.h>

#define B_ 2
#define T_ 2048
#define C_ 1024
#define H_ 16
#define D_ 64
#define M_ (B_*T_)          // 4096 rows
#define SCALE_ 0.125f       // 1/sqrt(64)
#define LOG2E_ 1.44269504f
#define NEG_ (-1e30f)
#define THR_ 8.0f           // defer-max threshold (log2 units)

typedef __bf16 bf16;
typedef __bf16 bf16x4 __attribute__((ext_vector_type(4)));
typedef __bf16 bf16x8 __attribute__((ext_vector_type(8)));
typedef float  f32x4  __attribute__((ext_vector_type(4)));

#define XB_ELEMS  ((size_t)M_*C_)        // 4,194,304
#define W_ELEMS   ((size_t)C_*C_)        // 1,048,576

__device__ __forceinline__ void glds16(const void* g, void* l) {
  __builtin_amdgcn_global_load_lds((const __attribute__((address_space(1))) void*)g,
                                   (__attribute__((address_space(3))) void*)l,
                                   16, 0, 0);
}

// ---------------------------------------------------------------------------
// f32 -> bf16 conversion pass (r16 version).
// ---------------------------------------------------------------------------
__global__ __launch_bounds__(256)
void cvt5(const float* __restrict__ x,  const float* __restrict__ wq,
          const float* __restrict__ wk, const float* __restrict__ wv,
          const float* __restrict__ wo, bf16* __restrict__ out,
          bf16* __restrict__ wodst) {
  int bid = blockIdx.x;
  const float* src; bf16* dst; size_t off;
  if (bid < 2048)      { src = x;  dst = out;                         off = (size_t)bid*2048; }
  else if (bid < 2560) { src = wq; dst = out + XB_ELEMS;              off = (size_t)(bid-2048)*2048; }
  else if (bid < 3072) { src = wk; dst = out + XB_ELEMS +   W_ELEMS;  off = (size_t)(bid-2560)*2048; }
  else if (bid < 3584) { src = wv; dst = out + XB_ELEMS + 2*W_ELEMS;  off = (size_t)(bid-3072)*2048; }
  else                 { src = wo; dst = wodst;                       off = (size_t)(bid-3584)*2048; }
  size_t i = off + (size_t)threadIdx.x * 8;
  f32x4 lo = *(const f32x4*)(src + i);
  f32x4 hi = *(const f32x4*)(src + i + 4);
  bf16x8 r;
  #pragma unroll
  for (int t = 0; t < 4; ++t) { r[t] = (bf16)lo[t]; r[t+4] = (bf16)hi[t]; }
  *(bf16x8*)(dst + i) = r;
}

// ---------------------------------------------------------------------------
// NT GEMM (r17 version): 128x128 tile, BK=64, 4 waves, glds16 pre-swizzled
// source + XOR-swizzled reads. 16 K-iterations.
// ---------------------------------------------------------------------------
template<int OUTMODE>
__global__ __launch_bounds__(256)
void gemm_nt(const bf16* __restrict__ Ab,
             const bf16* __restrict__ W0, const bf16* __restrict__ W1,
             const bf16* __restrict__ W2,
             void* __restrict__ O0v, void* __restrict__ O1v, void* __restrict__ O2v,
             int K) {
  __shared__ __align__(16) bf16 As[128*64];
  __shared__ __align__(16) bf16 Bs[128*64];

  const bf16* W = W0;
  void* Ov = O0v;
  bool vtrans = false;
  float oscale = 1.0f;
  if constexpr (OUTMODE == 0) {
    if (blockIdx.z == 0)      { oscale = SCALE_ * LOG2E_; }
    else if (blockIdx.z == 1) { W = W1; Ov = O1v; }
    else                      { W = W2; Ov = O2v; vtrans = true; }
  }

  const int m0 = blockIdx.y * 128, n0 = blockIdx.x * 128;
  const int tid = threadIdx.x, wid = tid >> 6, lane = tid & 63;
  const int wm = wid >> 1, wn = wid & 1;
  const int l15 = lane & 15, grp = lane >> 4;

  f32x4 acc[4][4] = {};

  const int lr8 = lane >> 3;
  const int lkswz = ((lane & 7) ^ lr8) * 8;
  const bf16* Ag = Ab + (size_t)(m0 + wid*8 + lr8) * K + lkswz;
  const bf16* Bg = W  + (size_t)(n0 + wid*8 + lr8) * K + lkswz;

  const int amRow = wm*64 + l15;
  const int bnRow = wn*64 + l15;
  const int swz = l15 & 7;

  for (int k0 = 0; k0 < K; k0 += 64) {
    __syncthreads();
    #pragma unroll
    for (int c = 0; c < 4; ++c) {
      glds16(Ag + (size_t)(c*32)*K + k0, As + (wid + c*4)*512);
      glds16(Bg + (size_t)(c*32)*K + k0, Bs + (wid + c*4)*512);
    }
    __syncthreads();

    #pragma unroll
    for (int ks = 0; ks < 2; ++ks) {
      const int aslot = ((ks*4 + grp) ^ swz) * 8;
      bf16x8 af[4], bfr[4];
      #pragma unroll
      for (int i = 0; i < 4; ++i) {
        af[i]  = *(const bf16x8*)(As + (amRow + i*16)*64 + aslot);
        bfr[i] = *(const bf16x8*)(Bs + (bnRow + i*16)*64 + aslot);
      }
      __builtin_amdgcn_s_setprio(1);
      #pragma unroll
      for (int i = 0; i < 4; ++i)
        #pragma unroll
        for (int j = 0; j < 4; ++j)
          acc[i][j] = __builtin_amdgcn_mfma_f32_16x16x32_bf16(af[i], bfr[j], acc[i][j], 0, 0, 0);
      __builtin_amdgcn_s_setprio(0);
    }
  }

  const int rBase = m0 + wm*64 + grp * 4;
  const int cBase = n0 + wn*64 + l15;
  #pragma unroll
  for (int fm = 0; fm < 4; ++fm) {
    #pragma unroll
    for (int fn = 0; fn < 4; ++fn) {
      #pragma unroll
      for (int j = 0; j < 4; ++j) {
        int m = rBase + fm*16 + j;
        int n = cBase + fn*16;
        if constexpr (OUTMODE == 0) {
          int b = m >> 11, t = m & 2047, h = n >> 6, d = n & 63;
          size_t idx = vtrans ? (((size_t)(b*H_ + h) * D_ + d) * T_ + t)
                              : (((size_t)(b*H_ + h) * T_ + t) * D_ + d);
          ((bf16*)Ov)[idx] = (bf16)(acc[fm][fn][j] * oscale);
        } else {
          ((float*)Ov)[(size_t)m * C_ + n] = acc[fm][fn][j];
        }
      }
    }
  }
}

// ---------------------------------------------------------------------------
// Flash attention, causal. QBLK=64, grid 1024 (LPT qt=31-(id>>5), bh=id&31).
// NEW staging: K/V double-buffered via glds16 (linear LDS dest, pre-swizzled
// global source, XOR-swizzled reads) -> ONE barrier per iteration, prefetch
// drains a full iteration after issue. P has the same 16B-slot XOR swizzle.
// LDS = 2*8K(K) + 2*8K(V) + 8K(P) = 40 KB -> 4 blocks/CU exactly.
// ---------------------------------------------------------------------------
__global__ __launch_bounds__(256)
void attn_fwd(const bf16* __restrict__ Q, const bf16* __restrict__ Km,
              const bf16* __restrict__ Vt, bf16* __restrict__ Oa) {
  __shared__ __align__(16) bf16 Kd[2][64*64];
  __shared__ __align__(16) bf16 Vd[2][64*64];
  __shared__ __align__(16) bf16 Ps[64*64];

  const int id = blockIdx.x;
  const int qt = 31 - (id >> 5);
  const int bh = id & 31;
  const int q0 = qt * 64;
  const int tid = threadIdx.x, wid = tid >> 6, lane = tid & 63;
  const int l15 = lane & 15;
  const int grp = lane >> 4;
  const int myrow4 = grp * 4;
  const int sw = l15 & 7;                 // row&7 for all fragment reads

  const bf16* Qb = Q  + (size_t)bh * T_ * D_;
  const bf16* Kb = Km + (size_t)bh * T_ * D_;
  const bf16* Vb = Vt + (size_t)bh * D_ * T_;

  const int b = bh >> 4, h = bh & 15;

  // glds16 staging geometry: chunk = 8 rows x 64 elems (1KB); wave w stages
  // chunks {w, w+4}. lane -> row_in_chunk r8 = lane>>3, phys slot = lane&7.
  // Source column pre-swizzled: logical slot = phys ^ r8.
  const int r8  = lane >> 3;
  const int csw = ((lane & 7) ^ r8) * 8;
  const bf16* KgA = Kb + (size_t)(wid*8     + r8)*64 + csw;
  const bf16* KgB = Kb + (size_t)((wid+4)*8 + r8)*64 + csw;
  const bf16* VgA = Vb + (size_t)(wid*8     + r8)*T_ + csw;
  const bf16* VgB = Vb + (size_t)((wid+4)*8 + r8)*T_ + csw;

  const int qrow = q0 + wid*16 + l15;
  bf16x8 aq0 = *(const bf16x8*)(Qb + (size_t)qrow*64 +      grp*8);
  bf16x8 aq1 = *(const bf16x8*)(Qb + (size_t)qrow*64 + 32 + grp*8);

  f32x4 oacc[4] = {};
  float m_s = NEG_, l_s = 0.f;

  // prologue: stage tile 0 into buffer 0
  glds16(KgA,  &Kd[0][wid*512]);
  glds16(KgB,  &Kd[0][(wid+4)*512]);
  glds16(VgA,  &Vd[0][wid*512]);
  glds16(VgB,  &Vd[0][(wid+4)*512]);

  for (int kt = 0; kt <= qt; ++kt) {
    const int kv0 = kt * 64;
    const int cur = kt & 1;

    __syncthreads();   // drains vmcnt: tile kt landed; prior reads complete

    if (kt < qt) {     // issue next tile into the other buffer (race-free:
      const int kn = kv0 + 64;           // its last readers finished pre-barrier)
      glds16(KgA + (size_t)kn*64, &Kd[cur^1][wid*512]);
      glds16(KgB + (size_t)kn*64, &Kd[cur^1][(wid+4)*512]);
      glds16(VgA + kn,            &Vd[cur^1][wid*512]);
      glds16(VgB + kn,            &Vd[cur^1][(wid+4)*512]);
    }

    const bf16* Kc = Kd[cur];
    const bf16* Vc = Vd[cur];

    // S^T = K Q^T (swizzled K reads)
    f32x4 s[4];
    __builtin_amdgcn_s_setprio(1);
    #pragma unroll
    for (int n = 0; n < 4; ++n) {
      int row = n*16 + l15;
      bf16x8 bk0 = *(const bf16x8*)(Kc + row*64 + ((grp     ^ sw)*8));
      bf16x8 bk1 = *(const bf16x8*)(Kc + row*64 + (((grp|4) ^ sw)*8));
      f32x4 a = {};
      a = __builtin_amdgcn_mfma_f32_16x16x32_bf16(bk0, aq0, a, 0, 0, 0);
      a = __builtin_amdgcn_mfma_f32_16x16x32_bf16(bk1, aq1, a, 0, 0, 0);
      s[n] = a;
    }
    __builtin_amdgcn_s_setprio(0);

    // mask (diag tile only) + row max
    float pmax = NEG_;
    if (kt == qt) {
      #pragma unroll
      for (int n = 0; n < 4; ++n)
        #pragma unroll
        for (int j = 0; j < 4; ++j) {
          int kvg = kv0 + n*16 + myrow4 + j;
          float sv = (kvg <= qrow) ? s[n][j] : NEG_;
          s[n][j] = sv;
          pmax = fmaxf(pmax, sv);
        }
    } else {
      #pragma unroll
      for (int n = 0; n < 4; ++n)
        #pragma unroll
        for (int j = 0; j < 4; ++j) pmax = fmaxf(pmax, s[n][j]);
    }
    pmax = fmaxf(pmax, __shfl_xor(pmax, 16));
    pmax = fmaxf(pmax, __shfl_xor(pmax, 32));

    // defer-max
    if (__any(pmax > m_s + THR_)) {
      float mnew = fmaxf(m_s, pmax);
      float scold = __builtin_amdgcn_exp2f(m_s - mnew);
      m_s = mnew;
      l_s *= scold;
      #pragma unroll
      for (int j = 0; j < 4; ++j) {
        float scj = __shfl(scold, myrow4 + j);
        #pragma unroll
        for (int n = 0; n < 4; ++n) oacc[n][j] *= scj;
      }
    }

    // p = 2^(s-m); row sum; P write (swizzled 16B slot, b64 per n)
    const int prow = wid*16 + l15;
    float ps = 0.f;
    #pragma unroll
    for (int n = 0; n < 4; ++n) {
      bf16x4 pw;
      #pragma unroll
      for (int j = 0; j < 4; ++j) {
        float p = __builtin_amdgcn_exp2f(s[n][j] - m_s);
        ps += p;
        pw[j] = (bf16)p;
      }
      int sl = (2*n + (grp >> 1)) ^ sw;
      *(bf16x4*)(Ps + prow*64 + sl*8 + (grp & 1)*4) = pw;
    }
    ps += __shfl_xor(ps, 16);
    ps += __shfl_xor(ps, 32);
    l_s += ps;

    asm volatile("s_waitcnt lgkmcnt(0)" ::: "memory");
    __builtin_amdgcn_sched_barrier(0);

    // O += P V (swizzled P and V reads)
    bf16x8 pa0 = *(const bf16x8*)(Ps + prow*64 + ((grp     ^ sw)*8));
    bf16x8 pa1 = *(const bf16x8*)(Ps + prow*64 + (((grp|4) ^ sw)*8));
    __builtin_amdgcn_s_setprio(1);
    #pragma unroll
    for (int n = 0; n < 4; ++n) {
      int vrow = n*16 + l15;
      bf16x8 bv0 = *(const bf16x8*)(Vc + vrow*64 + ((grp     ^ sw)*8));
      bf16x8 bv1 = *(const bf16x8*)(Vc + vrow*64 + (((grp|4) ^ sw)*8));
      oacc[n] = __builtin_amdgcn_mfma_f32_16x16x32_bf16(pa0, bv0, oacc[n], 0, 0, 0);
      oacc[n] = __builtin_amdgcn_mfma_f32_16x16x32_bf16(pa1, bv1, oacc[n], 0, 0, 0);
    }
    __builtin_amdgcn_s_setprio(0);
  }

  // epilogue: O /= l -> bf16 [B,T,C]
  const int tg = q0 + wid*16 + myrow4;
  #pragma unroll
  for (int j = 0; j < 4; ++j) {
    float lj = __shfl(l_s, myrow4 + j);
    float inv = 1.f / lj;
    int trow = tg + j;
    #pragma unroll
    for (int n = 0; n < 4; ++n) {
      int ch = h*64 + n*16 + l15;
      Oa[((size_t)(b*T_ + trow)) * C_ + ch] = (bf16)(oacc[n][j] * inv);
    }
  }
}

// ---------------------------------------------------------------------------
extern "C" void kernel_launch(void* const* d_in, const int* in_sizes, int n_in,
                              void* d_out, int out_size, void* d_ws, size_t ws_size,
                              hipStream_t stream) {
  const float* x  = (const float*)d_in[0];
  const float* wq = (const float*)d_in[1];
  const float* wk = (const float*)d_in[2];
  const float* wv = (const float*)d_in[3];
  const float* wo = (const float*)d_in[4];

  bf16* q  = (bf16*)d_ws;                    // [B,H,T,D] bf16 (Q pre-scaled)
  bf16* k  = q  + XB_ELEMS;
  bf16* v  = k  + XB_ELEMS;                  // [B,H,D,T] bf16 (transposed)

  bf16* cvtbuf = (bf16*)d_out;               // bf16 staging inside d_out
  bf16* xb  = cvtbuf;
  bf16* wqb = cvtbuf + XB_ELEMS;
  bf16* wkb = wqb + W_ELEMS;
  bf16* wvb = wkb + W_ELEMS;
  bf16* wob_stage = wvb + W_ELEMS;           // fallback wo staging (in d_out)

  const bool bigws = ws_size >= (4*XB_ELEMS + W_ELEMS) * sizeof(bf16);
  bf16* ao  = bigws ? (v + XB_ELEMS) : xb;
  bf16* wob = bigws ? (v + 2*XB_ELEMS) : wob_stage;

  dim3 blk(256);
  // 0) convert all f32 inputs to bf16
  cvt5<<<dim3(4096), blk, 0, stream>>>(x, wq, wk, wv, wo, cvtbuf, wob);
  // 1) QKV projections: xb @ W^T -> q,k,v
  gemm_nt<0><<<dim3(C_/128, M_/128, 3), blk, 0, stream>>>(xb, wqb, wkb, wvb,
                                                          q, k, v, C_);
  // 2) causal flash attention -> ao bf16 [B,T,C]
  attn_fwd<<<dim3(1024), blk, 0, stream>>>(q, k, v, ao);
  bf16* aoSrc = ao;
  if (!bigws) {
    hipMemcpyAsync(q, xb,        XB_ELEMS * sizeof(bf16), hipMemcpyDeviceToDevice, stream);
    hipMemcpyAsync(k, wob_stage, W_ELEMS  * sizeof(bf16), hipMemcpyDeviceToDevice, stream);
    aoSrc = q; wob = k;
  }
  // 3) output projection: ao @ wo^T -> f32 d_out
  gemm_nt<1><<<dim3(C_/128, M_/128, 1), blk, 0, stream>>>(aoSrc, wob, nullptr, nullptr,
                                                          d_out, nullptr, nullptr, C_);
}

// Round 20
// 110.547 us; speedup vs baseline: 1.1311x; 1.0358x over previous
//
#include <hip/hip_runtime.h>
#include <hip/hip_bf16.h>

#define B_ 2
#define T_ 2048
#define C_ 1024
#define H_ 16
#define D_ 64
#define M_ (B_*T_)          // 4096 rows
#define SCALE_ 0.125f       // 1/sqrt(64)
#define LOG2E_ 1.44269504f
#define NEG_ (-1e30f)
#define THR_ 8.0f           // defer-max threshold (log2 units)

typedef __bf16 bf16;
typedef __bf16 bf16x4 __attribute__((ext_vector_type(4)));
typedef __bf16 bf16x8 __attribute__((ext_vector_type(8)));
typedef float  f32x4  __attribute__((ext_vector_type(4)));

#define XB_ELEMS  ((size_t)M_*C_)        // 4,194,304
#define W_ELEMS   ((size_t)C_*C_)        // 1,048,576

__device__ __forceinline__ void glds16(const void* g, void* l) {
  __builtin_amdgcn_global_load_lds((const __attribute__((address_space(1))) void*)g,
                                   (__attribute__((address_space(3))) void*)l,
                                   16, 0, 0);
}

// ---------------------------------------------------------------------------
// f32 -> bf16 conversion pass (r16 version).
// ---------------------------------------------------------------------------
__global__ __launch_bounds__(256)
void cvt5(const float* __restrict__ x,  const float* __restrict__ wq,
          const float* __restrict__ wk, const float* __restrict__ wv,
          const float* __restrict__ wo, bf16* __restrict__ out,
          bf16* __restrict__ wodst) {
  int bid = blockIdx.x;
  const float* src; bf16* dst; size_t off;
  if (bid < 2048)      { src = x;  dst = out;                         off = (size_t)bid*2048; }
  else if (bid < 2560) { src = wq; dst = out + XB_ELEMS;              off = (size_t)(bid-2048)*2048; }
  else if (bid < 3072) { src = wk; dst = out + XB_ELEMS +   W_ELEMS;  off = (size_t)(bid-2560)*2048; }
  else if (bid < 3584) { src = wv; dst = out + XB_ELEMS + 2*W_ELEMS;  off = (size_t)(bid-3072)*2048; }
  else                 { src = wo; dst = wodst;                       off = (size_t)(bid-3584)*2048; }
  size_t i = off + (size_t)threadIdx.x * 8;
  f32x4 lo = *(const f32x4*)(src + i);
  f32x4 hi = *(const f32x4*)(src + i + 4);
  bf16x8 r;
  #pragma unroll
  for (int t = 0; t < 4; ++t) { r[t] = (bf16)lo[t]; r[t+4] = (bf16)hi[t]; }
  *(bf16x8*)(dst + i) = r;
}

// ---------------------------------------------------------------------------
// NT GEMM (r17 version, unchanged): 128x128, BK=64, 4 waves, glds16
// pre-swizzled source + XOR-swizzled reads. 16 K-iterations.
// ---------------------------------------------------------------------------
template<int OUTMODE>
__global__ __launch_bounds__(256)
void gemm_nt(const bf16* __restrict__ Ab,
             const bf16* __restrict__ W0, const bf16* __restrict__ W1,
             const bf16* __restrict__ W2,
             void* __restrict__ O0v, void* __restrict__ O1v, void* __restrict__ O2v,
             int K) {
  __shared__ __align__(16) bf16 As[128*64];
  __shared__ __align__(16) bf16 Bs[128*64];

  const bf16* W = W0;
  void* Ov = O0v;
  bool vtrans = false;
  float oscale = 1.0f;
  if constexpr (OUTMODE == 0) {
    if (blockIdx.z == 0)      { oscale = SCALE_ * LOG2E_; }
    else if (blockIdx.z == 1) { W = W1; Ov = O1v; }
    else                      { W = W2; Ov = O2v; vtrans = true; }
  }

  const int m0 = blockIdx.y * 128, n0 = blockIdx.x * 128;
  const int tid = threadIdx.x, wid = tid >> 6, lane = tid & 63;
  const int wm = wid >> 1, wn = wid & 1;
  const int l15 = lane & 15, grp = lane >> 4;

  f32x4 acc[4][4] = {};

  const int lr8 = lane >> 3;
  const int lkswz = ((lane & 7) ^ lr8) * 8;
  const bf16* Ag = Ab + (size_t)(m0 + wid*8 + lr8) * K + lkswz;
  const bf16* Bg = W  + (size_t)(n0 + wid*8 + lr8) * K + lkswz;

  const int amRow = wm*64 + l15;
  const int bnRow = wn*64 + l15;
  const int swz = l15 & 7;

  for (int k0 = 0; k0 < K; k0 += 64) {
    __syncthreads();
    #pragma unroll
    for (int c = 0; c < 4; ++c) {
      glds16(Ag + (size_t)(c*32)*K + k0, As + (wid + c*4)*512);
      glds16(Bg + (size_t)(c*32)*K + k0, Bs + (wid + c*4)*512);
    }
    __syncthreads();

    #pragma unroll
    for (int ks = 0; ks < 2; ++ks) {
      const int aslot = ((ks*4 + grp) ^ swz) * 8;
      bf16x8 af[4], bfr[4];
      #pragma unroll
      for (int i = 0; i < 4; ++i) {
        af[i]  = *(const bf16x8*)(As + (amRow + i*16)*64 + aslot);
        bfr[i] = *(const bf16x8*)(Bs + (bnRow + i*16)*64 + aslot);
      }
      __builtin_amdgcn_s_setprio(1);
      #pragma unroll
      for (int i = 0; i < 4; ++i)
        #pragma unroll
        for (int j = 0; j < 4; ++j)
          acc[i][j] = __builtin_amdgcn_mfma_f32_16x16x32_bf16(af[i], bfr[j], acc[i][j], 0, 0, 0);
      __builtin_amdgcn_s_setprio(0);
    }
  }

  const int rBase = m0 + wm*64 + grp * 4;
  const int cBase = n0 + wn*64 + l15;
  #pragma unroll
  for (int fm = 0; fm < 4; ++fm) {
    #pragma unroll
    for (int fn = 0; fn < 4; ++fn) {
      #pragma unroll
      for (int j = 0; j < 4; ++j) {
        int m = rBase + fm*16 + j;
        int n = cBase + fn*16;
        if constexpr (OUTMODE == 0) {
          int b = m >> 11, t = m & 2047, h = n >> 6, d = n & 63;
          size_t idx = vtrans ? (((size_t)(b*H_ + h) * D_ + d) * T_ + t)
                              : (((size_t)(b*H_ + h) * T_ + t) * D_ + d);
          ((bf16*)Ov)[idx] = (bf16)(acc[fm][fn][j] * oscale);
        } else {
          ((float*)Ov)[(size_t)m * C_ + n] = acc[fm][fn][j];
        }
      }
    }
  }
}

// ---------------------------------------------------------------------------
// Flash attention, causal. r17 structure (QBLK=64, grid 1024 LPT, 2 barriers,
// reg-prefetch staging) with r19's XOR swizzles on an UNPADDED [64][64]
// layout: staging writes at slot^(row&7), all reads at slot^(row&7), P at
// r19's slot map. LDS = 24 KB. Removes the 8/16-way write conflicts.
// ---------------------------------------------------------------------------
__global__ __launch_bounds__(256)
void attn_fwd(const bf16* __restrict__ Q, const bf16* __restrict__ Km,
              const bf16* __restrict__ Vt, bf16* __restrict__ Oa) {
  __shared__ __align__(16) bf16 Ks [64*64];
  __shared__ __align__(16) bf16 Vts[64*64];
  __shared__ __align__(16) bf16 Ps [64*64];

  const int id = blockIdx.x;
  const int qt = 31 - (id >> 5);
  const int bh = id & 31;
  const int q0 = qt * 64;
  const int tid = threadIdx.x, wid = tid >> 6, lane = tid & 63;
  const int l15 = lane & 15;
  const int grp = lane >> 4;
  const int myrow4 = grp * 4;
  const int sw = l15 & 7;                 // row&7 for fragment reads

  const bf16* Qb = Q  + (size_t)bh * T_ * D_;
  const bf16* Kb = Km + (size_t)bh * T_ * D_;
  const bf16* Vb = Vt + (size_t)bh * D_ * T_;

  // staging: thread t -> local rows ksr, ksr+32 (ksr = t>>3), 16B chunk t&7
  const int ksr = tid >> 3, kskc = tid & 7;
  const int wsl = (kskc ^ (ksr & 7)) * 8;  // swizzled write slot (both rows:
                                           // (ksr+32)&7 == ksr&7)
  const int b = bh >> 4, h = bh & 15;

  const int qrow = q0 + wid*16 + l15;
  bf16x8 aq0 = *(const bf16x8*)(Qb + (size_t)qrow*64 +      grp*8);
  bf16x8 aq1 = *(const bf16x8*)(Qb + (size_t)qrow*64 + 32 + grp*8);

  f32x4 oacc[4] = {};
  float m_s = NEG_, l_s = 0.f;

  bf16x8 kv_a = *(const bf16x8*)(Kb + (size_t)(ksr)*64      + kskc*8);
  bf16x8 kv_b = *(const bf16x8*)(Kb + (size_t)(ksr + 32)*64 + kskc*8);
  bf16x8 vt_a = *(const bf16x8*)(Vb + (size_t)(ksr     )*T_ + kskc*8);
  bf16x8 vt_b = *(const bf16x8*)(Vb + (size_t)(ksr + 32)*T_ + kskc*8);

  for (int kt = 0; kt <= qt; ++kt) {
    const int kv0 = kt * 64;

    __syncthreads();
    *(bf16x8*)(Ks  + ksr*64      + wsl) = kv_a;
    *(bf16x8*)(Ks  + (ksr+32)*64 + wsl) = kv_b;
    *(bf16x8*)(Vts + ksr*64      + wsl) = vt_a;
    *(bf16x8*)(Vts + (ksr+32)*64 + wsl) = vt_b;
    __syncthreads();

    {   // prefetch next tile into regs (lands during this iter's compute)
      const int kn = (kt < qt) ? kv0 + 64 : kv0;
      kv_a = *(const bf16x8*)(Kb + (size_t)(kn + ksr)*64      + kskc*8);
      kv_b = *(const bf16x8*)(Kb + (size_t)(kn + ksr + 32)*64 + kskc*8);
      vt_a = *(const bf16x8*)(Vb + (size_t)(ksr     )*T_ + kn + kskc*8);
      vt_b = *(const bf16x8*)(Vb + (size_t)(ksr + 32)*T_ + kn + kskc*8);
    }

    // S^T = K Q^T (swizzled K reads)
    f32x4 s[4];
    __builtin_amdgcn_s_setprio(1);
    #pragma unroll
    for (int n = 0; n < 4; ++n) {
      int row = n*16 + l15;
      bf16x8 bk0 = *(const bf16x8*)(Ks + row*64 + ((grp     ^ sw)*8));
      bf16x8 bk1 = *(const bf16x8*)(Ks + row*64 + (((grp|4) ^ sw)*8));
      f32x4 a = {};
      a = __builtin_amdgcn_mfma_f32_16x16x32_bf16(bk0, aq0, a, 0, 0, 0);
      a = __builtin_amdgcn_mfma_f32_16x16x32_bf16(bk1, aq1, a, 0, 0, 0);
      s[n] = a;
    }
    __builtin_amdgcn_s_setprio(0);

    // mask (diag tile only) + row max
    float pmax = NEG_;
    if (kt == qt) {
      #pragma unroll
      for (int n = 0; n < 4; ++n)
        #pragma unroll
        for (int j = 0; j < 4; ++j) {
          int kvg = kv0 + n*16 + myrow4 + j;
          float sv = (kvg <= qrow) ? s[n][j] : NEG_;
          s[n][j] = sv;
          pmax = fmaxf(pmax, sv);
        }
    } else {
      #pragma unroll
      for (int n = 0; n < 4; ++n)
        #pragma unroll
        for (int j = 0; j < 4; ++j) pmax = fmaxf(pmax, s[n][j]);
    }
    pmax = fmaxf(pmax, __shfl_xor(pmax, 16));
    pmax = fmaxf(pmax, __shfl_xor(pmax, 32));

    // defer-max
    if (__any(pmax > m_s + THR_)) {
      float mnew = fmaxf(m_s, pmax);
      float scold = __builtin_amdgcn_exp2f(m_s - mnew);
      m_s = mnew;
      l_s *= scold;
      #pragma unroll
      for (int j = 0; j < 4; ++j) {
        float scj = __shfl(scold, myrow4 + j);
        #pragma unroll
        for (int n = 0; n < 4; ++n) oacc[n][j] *= scj;
      }
    }

    // p = 2^(s-m); row sum; P write (swizzled 16B slot, b64 per n)
    const int prow = wid*16 + l15;
    float ps = 0.f;
    #pragma unroll
    for (int n = 0; n < 4; ++n) {
      bf16x4 pw;
      #pragma unroll
      for (int j = 0; j < 4; ++j) {
        float p = __builtin_amdgcn_exp2f(s[n][j] - m_s);
        ps += p;
        pw[j] = (bf16)p;
      }
      int sl = (2*n + (grp >> 1)) ^ sw;
      *(bf16x4*)(Ps + prow*64 + sl*8 + (grp & 1)*4) = pw;
    }
    ps += __shfl_xor(ps, 16);
    ps += __shfl_xor(ps, 32);
    l_s += ps;

    asm volatile("s_waitcnt lgkmcnt(0)" ::: "memory");
    __builtin_amdgcn_sched_barrier(0);

    // O += P V (swizzled P and V reads)
    bf16x8 pa0 = *(const bf16x8*)(Ps + prow*64 + ((grp     ^ sw)*8));
    bf16x8 pa1 = *(const bf16x8*)(Ps + prow*64 + (((grp|4) ^ sw)*8));
    __builtin_amdgcn_s_setprio(1);
    #pragma unroll
    for (int n = 0; n < 4; ++n) {
      int vrow = n*16 + l15;
      bf16x8 bv0 = *(const bf16x8*)(Vts + vrow*64 + ((grp     ^ sw)*8));
      bf16x8 bv1 = *(const bf16x8*)(Vts + vrow*64 + (((grp|4) ^ sw)*8));
      oacc[n] = __builtin_amdgcn_mfma_f32_16x16x32_bf16(pa0, bv0, oacc[n], 0, 0, 0);
      oacc[n] = __builtin_amdgcn_mfma_f32_16x16x32_bf16(pa1, bv1, oacc[n], 0, 0, 0);
    }
    __builtin_amdgcn_s_setprio(0);
  }

  // epilogue: O /= l -> bf16 [B,T,C]
  const int tg = q0 + wid*16 + myrow4;
  #pragma unroll
  for (int j = 0; j < 4; ++j) {
    float lj = __shfl(l_s, myrow4 + j);
    float inv = 1.f / lj;
    int trow = tg + j;
    #pragma unroll
    for (int n = 0; n < 4; ++n) {
      int ch = h*64 + n*16 + l15;
      Oa[((size_t)(b*T_ + trow)) * C_ + ch] = (bf16)(oacc[n][j] * inv);
    }
  }
}

// ---------------------------------------------------------------------------
extern "C" void kernel_launch(void* const* d_in, const int* in_sizes, int n_in,
                              void* d_out, int out_size, void* d_ws, size_t ws_size,
                              hipStream_t stream) {
  const float* x  = (const float*)d_in[0];
  const float* wq = (const float*)d_in[1];
  const float* wk = (const float*)d_in[2];
  const float* wv = (const float*)d_in[3];
  const float* wo = (const float*)d_in[4];

  bf16* q  = (bf16*)d_ws;                    // [B,H,T,D] bf16 (Q pre-scaled)
  bf16* k  = q  + XB_ELEMS;
  bf16* v  = k  + XB_ELEMS;                  // [B,H,D,T] bf16 (transposed)

  bf16* cvtbuf = (bf16*)d_out;               // bf16 staging inside d_out
  bf16* xb  = cvtbuf;
  bf16* wqb = cvtbuf + XB_ELEMS;
  bf16* wkb = wqb + W_ELEMS;
  bf16* wvb = wkb + W_ELEMS;
  bf16* wob_stage = wvb + W_ELEMS;           // fallback wo staging (in d_out)

  const bool bigws = ws_size >= (4*XB_ELEMS + W_ELEMS) * sizeof(bf16);
  bf16* ao  = bigws ? (v + XB_ELEMS) : xb;
  bf16* wob = bigws ? (v + 2*XB_ELEMS) : wob_stage;

  dim3 blk(256);
  // 0) convert all f32 inputs to bf16
  cvt5<<<dim3(4096), blk, 0, stream>>>(x, wq, wk, wv, wo, cvtbuf, wob);
  // 1) QKV projections: xb @ W^T -> q,k,v
  gemm_nt<0><<<dim3(C_/128, M_/128, 3), blk, 0, stream>>>(xb, wqb, wkb, wvb,
                                                          q, k, v, C_);
  // 2) causal flash attention -> ao bf16 [B,T,C]
  attn_fwd<<<dim3(1024), blk, 0, stream>>>(q, k, v, ao);
  bf16* aoSrc = ao;
  if (!bigws) {
    hipMemcpyAsync(q, xb,        XB_ELEMS * sizeof(bf16), hipMemcpyDeviceToDevice, stream);
    hipMemcpyAsync(k, wob_stage, W_ELEMS  * sizeof(bf16), hipMemcpyDeviceToDevice, stream);
    aoSrc = q; wob = k;
  }
  // 3) output projection: ao @ wo^T -> f32 d_out
  gemm_nt<1><<<dim3(C_/128, M_/128, 1), blk, 0, stream>>>(aoSrc, wob, nullptr, nullptr,
                                                          d_out, nullptr, nullptr, C_);
}